// Round 5
// baseline (372.113 us; speedup 1.0000x reference)
//
#include <hip/hip_runtime.h>
#include <math.h>

#define HDIM 512
#define NROWS 100000
#define NBLK_A 2048
#define NBLK_B 64

// ---- workspace layout (float indices) ----
constexpr int SIMS_OFF   = 0;                        // [NROWS] sims = -||K-cue||^2
constexpr int BMIN_OFF   = NROWS;                    // [NBLK_A] per-block min ||K-cue||^2
constexpr int CNT_OFF    = BMIN_OFF + NBLK_A;        // [2] int tickets (memset to 0 host-side)
constexpr int PREACT_OFF = CNT_OFF + 2;              // [5*HDIM]
constexpr int PM_OFF     = PREACT_OFF + 5 * HDIM;    // [NBLK_B*HDIM] partial e*V
constexpr int PD_OFF     = PM_OFF + NBLK_B * HDIM;   // [NBLK_B] partial e

__device__ __forceinline__ float wave_sum(float v) {
    #pragma unroll
    for (int off = 32; off; off >>= 1) v += __shfl_xor(v, off);
    return v;
}
__device__ __forceinline__ float wave_min(float v) {
    #pragma unroll
    for (int off = 32; off; off >>= 1) v = fminf(v, __shfl_xor(v, off));
    return v;
}
__device__ __forceinline__ float d2sum(float4 a, float4 c) {
    float d, s;
    d = a.x - c.x; s  = d * d;
    d = a.y - c.y; s += d * d;
    d = a.z - c.z; s += d * d;
    d = a.w - c.w; s += d * d;
    return s;
}

__global__ __launch_bounds__(256, 6)
void kF(const float* __restrict__ state, const float* __restrict__ pa,
        const float* __restrict__ pr, const float* __restrict__ ts,
        const float* __restrict__ cue, const float* __restrict__ K,
        const float* __restrict__ V, const float* __restrict__ Wx,
        const float* __restrict__ Wh, const float* __restrict__ b,
        const float* __restrict__ aw, const float* __restrict__ ab,
        const float* __restrict__ cw, const float* __restrict__ cb,
        const float* __restrict__ h0, const float* __restrict__ c0,
        float* __restrict__ ws, float* __restrict__ out) {
    const int lane = threadIdx.x & 63;
    const int wib  = threadIdx.x >> 6;
    const int gw   = blockIdx.x * 4 + wib;
    const int nw   = NBLK_A * 4;                 // 8192 waves
    int* cnt1 = (int*)ws + CNT_OFF;
    int* cnt2 = (int*)ws + CNT_OFF + 1;

    // ======== phase 1a: preact rows (first 2560 waves; hides under sweep) ====
    if (gw < 5 * HDIM) {
        const int row = gw;
        float x0 = state[lane];
        float x1 = 0.f;
        if      (lane < 4)  x1 = pa[lane];
        else if (lane == 4) x1 = pr[0];
        else if (lane == 5) x1 = ts[0];

        const float4* h04 = (const float4*)h0;
        const float4  hA = h04[lane], hB = h04[64 + lane];
        const float4* wh4 = (const float4*)(Wh + (size_t)row * HDIM);
        const float4 a0 = wh4[lane], a1 = wh4[64 + lane];
        float acc = a0.x*hA.x + a0.y*hA.y + a0.z*hA.z + a0.w*hA.w
                  + a1.x*hB.x + a1.y*hB.y + a1.z*hB.z + a1.w*hB.w;
        const float* wxr = Wx + (size_t)row * 70;
        acc += wxr[lane] * x0;
        if (lane < 6) acc += wxr[64 + lane] * x1;
        acc = wave_sum(acc);
        if (lane == 0) ws[PREACT_OFF + row] = acc + b[row];
    }

    // ======== phase 1b: sims sweep (identical hot loop to round 4) ==========
    {
        const float4* c4 = (const float4*)cue;
        const float4 cA = c4[lane], cB = c4[64 + lane];
        float minss = INFINITY;

        const int NG = NROWS / 4;                // 25000 groups (NROWS % 4 == 0)
        for (int g = gw; g < NG; g += nw) {
            const int n = g * 4;                 // rows n..n+3
            const float* r = K + (size_t)n * HDIM;
            const float4* p0 = (const float4*)(r);
            const float4* p1 = (const float4*)(r + HDIM);
            const float4* p2 = (const float4*)(r + 2 * HDIM);
            const float4* p3 = (const float4*)(r + 3 * HDIM);
            const float4 a0 = p0[lane], b0 = p0[64 + lane];
            const float4 a1 = p1[lane], b1 = p1[64 + lane];
            const float4 a2 = p2[lane], b2 = p2[64 + lane];
            const float4 a3 = p3[lane], b3 = p3[64 + lane];
            float s0 = d2sum(a0, cA) + d2sum(b0, cB);
            float s1 = d2sum(a1, cA) + d2sum(b1, cB);
            float s2 = d2sum(a2, cA) + d2sum(b2, cB);
            float s3 = d2sum(a3, cA) + d2sum(b3, cB);
            #pragma unroll
            for (int off = 32; off; off >>= 1) { // 4 independent chains, ILP
                s0 += __shfl_xor(s0, off);
                s1 += __shfl_xor(s1, off);
                s2 += __shfl_xor(s2, off);
                s3 += __shfl_xor(s3, off);
            }
            if (lane == 0) {                     // n%4==0 -> 16B aligned
                *(float4*)&ws[SIMS_OFF + n] = make_float4(-s0, -s1, -s2, -s3);
            }
            minss = fminf(fminf(minss, s0), fminf(fminf(s1, s2), s3));
        }

        minss = wave_min(minss);
        __shared__ float smin[4];
        if (lane == 0) smin[wib] = minss;
        __syncthreads();
        if (threadIdx.x == 0)
            ws[BMIN_OFF + blockIdx.x] =
                fminf(fminf(smin[0], smin[1]), fminf(smin[2], smin[3]));
    }

    // ======== ticket 1: last NBLK_B finishers become gather slots ============
    __threadfence();                             // release sims + bmin
    __shared__ int sT;
    if (threadIdx.x == 0) sT = atomicAdd(cnt1, 1);
    __syncthreads();
    const int slot = sT - (NBLK_A - NBLK_B);
    if (slot < 0) return;

    if (threadIdx.x == 0) {                      // wait for ALL blocks' sims
        while (__hip_atomic_load(cnt1, __ATOMIC_RELAXED,
                                 __HIP_MEMORY_SCOPE_AGENT) < NBLK_A)
            __builtin_amdgcn_s_sleep(8);
    }
    __syncthreads();
    __threadfence();                             // acquire all sims + bmins

    // ======== phase 2: global max + gather (keyed by slot — deterministic) ==
    const int t = threadIdx.x;
    float mn = INFINITY;
    #pragma unroll
    for (int i = 0; i < NBLK_A / 256; i++)
        mn = fminf(mn, ws[BMIN_OFF + i * 256 + t]);
    mn = wave_min(mn);
    __shared__ float sred[4];
    if (lane == 0) sred[wib] = mn;
    __syncthreads();
    const float smax = -fminf(fminf(sred[0], sred[1]), fminf(sred[2], sred[3]));

    const int gwid = slot * 4 + wib;             // 256 gather waves
    float4 accA = {0.f,0.f,0.f,0.f}, accB = {0.f,0.f,0.f,0.f};
    float dsum = 0.f;

    const int nchunks = (NROWS + 63) / 64;
    for (int c = gwid; c < nchunks; c += NBLK_B * 4) {
        const int n = c * 64 + lane;
        const bool valid = (n < NROWS);
        const float s = valid ? ws[SIMS_OFF + n] : -INFINITY;
        const float e = expf(s - smax);          // underflows to 0 for far rows
        dsum += e;                                // exact denominator
        unsigned long long mask = __ballot(valid && (s - smax >= -30.0f));
        while (mask) {
            const int bpos = __ffsll(mask) - 1;
            mask &= mask - 1;
            const int nb = c * 64 + bpos;
            const float eb = __shfl(e, bpos);
            const float4* v4 = (const float4*)(V + (size_t)nb * HDIM);
            const float4 vA = v4[lane], vB = v4[64 + lane];
            accA.x += eb * vA.x; accA.y += eb * vA.y;
            accA.z += eb * vA.z; accA.w += eb * vA.w;
            accB.x += eb * vB.x; accB.y += eb * vB.y;
            accB.z += eb * vB.z; accB.w += eb * vB.w;
        }
    }
    dsum = wave_sum(dsum);

    __shared__ float lm[4][HDIM];
    __shared__ float ld[4];
    {
        float* rowp = lm[wib];
        rowp[lane*4 + 0]       = accA.x; rowp[lane*4 + 1]       = accA.y;
        rowp[lane*4 + 2]       = accA.z; rowp[lane*4 + 3]       = accA.w;
        rowp[256 + lane*4 + 0] = accB.x; rowp[256 + lane*4 + 1] = accB.y;
        rowp[256 + lane*4 + 2] = accB.z; rowp[256 + lane*4 + 3] = accB.w;
        if (lane == 0) ld[wib] = dsum;
    }
    __syncthreads();

    ws[PM_OFF + slot * HDIM + t] =
        lm[0][t] + lm[1][t] + lm[2][t] + lm[3][t];
    ws[PM_OFF + slot * HDIM + 256 + t] =
        lm[0][256+t] + lm[1][256+t] + lm[2][256+t] + lm[3][256+t];
    if (t == 0)
        ws[PD_OFF + slot] = ld[0] + ld[1] + ld[2] + ld[3];

    // ======== ticket 2: last gather slot does the final ======================
    __threadfence();                             // release partials
    if (t == 0) sT = atomicAdd(cnt2, 1);
    __syncthreads();
    if (sT != NBLK_B - 1) return;
    __threadfence();                             // acquire partials

    __shared__ float hl[HDIM];
    __shared__ float sden;
    __shared__ float logits[4];

    if (wib == 0) {
        float d = ws[PD_OFF + lane];             // 64 partials, one per lane
        d = wave_sum(d);
        if (lane == 0) sden = d;
    }
    float m0 = 0.f, m1 = 0.f;
    #pragma unroll 8
    for (int b2 = 0; b2 < NBLK_B; b2++) {
        m0 += ws[PM_OFF + b2 * HDIM + t];
        m1 += ws[PM_OFF + b2 * HDIM + 256 + t];
    }
    __syncthreads();
    const float inv_den = 1.f / sden;
    m0 *= inv_den; m1 *= inv_den;

    #pragma unroll
    for (int half = 0; half < 2; half++) {
        const int tt = t + half * 256;
        const float mm = half ? m1 : m0;
        const float pf = ws[PREACT_OFF + tt];
        const float pi = ws[PREACT_OFF + HDIM + tt];
        const float po = ws[PREACT_OFF + 2*HDIM + tt];
        const float prg= ws[PREACT_OFF + 3*HDIM + tt];
        const float pc = ws[PREACT_OFF + 4*HDIM + tt];
        const float f_t = 1.f / (1.f + expf(-pf));
        const float i_t = 1.f / (1.f + expf(-pi));
        const float o_t = 1.f / (1.f + expf(-po));
        const float r_t = 1.f / (1.f + expf(-prg));
        const float chat = tanhf(pc);
        const float ct = f_t * c0[tt] + i_t * chat + r_t * mm;
        const float ht = o_t * tanhf(ct);
        out[517 + tt] = ct;
        out[5 + tt]   = ht;
        hl[tt] = ht;
    }
    __syncthreads();

    if (wib < 4) {       // actor logits, one wave per row
        float acc = 0.f;
        #pragma unroll
        for (int j = 0; j < HDIM; j += 64)
            acc += aw[wib * HDIM + j + lane] * hl[j + lane];
        acc = wave_sum(acc);
        if (lane == 0) logits[wib] = acc + ab[wib];
    }
    if (wib == 0) {      // critic
        float acc = 0.f;
        #pragma unroll
        for (int j = 0; j < HDIM; j += 64)
            acc += cw[j + lane] * hl[j + lane];
        acc = wave_sum(acc);
        if (lane == 0) out[4] = acc + cb[0];
    }
    __syncthreads();

    if (t == 0) {
        const float mx = fmaxf(fmaxf(logits[0], logits[1]),
                               fmaxf(logits[2], logits[3]));
        const float e0 = expf(logits[0] - mx), e1 = expf(logits[1] - mx);
        const float e2 = expf(logits[2] - mx), e3 = expf(logits[3] - mx);
        const float inv = 1.f / (e0 + e1 + e2 + e3);
        out[0] = e0 * inv; out[1] = e1 * inv;
        out[2] = e2 * inv; out[3] = e3 * inv;
    }
}

extern "C" void kernel_launch(void* const* d_in, const int* in_sizes, int n_in,
                              void* d_out, int out_size, void* d_ws, size_t ws_size,
                              hipStream_t stream) {
    const float* state  = (const float*)d_in[0];
    const float* pa     = (const float*)d_in[1];
    const float* pr     = (const float*)d_in[2];
    const float* ts     = (const float*)d_in[3];
    const float* cue    = (const float*)d_in[4];
    const float* keys   = (const float*)d_in[5];
    const float* vals   = (const float*)d_in[6];
    const float* Wx     = (const float*)d_in[7];
    const float* Wh     = (const float*)d_in[8];
    const float* b      = (const float*)d_in[9];
    const float* aw     = (const float*)d_in[10];
    const float* ab     = (const float*)d_in[11];
    const float* cw     = (const float*)d_in[12];
    const float* cb     = (const float*)d_in[13];
    const float* h0     = (const float*)d_in[14];
    const float* c0     = (const float*)d_in[15];
    float* ws  = (float*)d_ws;
    float* out = (float*)d_out;

    // zero the two ticket counters (8 bytes) — stream-ordered, capturable
    (void)hipMemsetAsync((int*)ws + CNT_OFF, 0, 2 * sizeof(int), stream);

    kF<<<NBLK_A, 256, 0, stream>>>(state, pa, pr, ts, cue, keys, vals,
                                   Wx, Wh, b, aw, ab, cw, cb, h0, c0, ws, out);
}

// Round 6
// 71.939 us; speedup vs baseline: 5.1726x; 5.1726x over previous
//
#include <hip/hip_runtime.h>
#include <math.h>

#define HDIM 512
#define NROWS 100000
#define NBLK_A 2048
#define K_CAP 1024           // max survivors kB can hold (data: ~3)

// region split: blocks [0,640) also do preact, so they get fewer key rows.
// 640*45.73 ~= 29268 rows for them, remaining 70732 over 1408 blocks.
#define SPLIT_ROWS 29268
#define SPLIT_BLKS 640

// ---- workspace layout (float indices) ----
constexpr int BMIN_OFF   = 0;                    // [NBLK_A] per-block min ||K-cue||^2
constexpr int CNT_OFF    = NBLK_A;               // [NBLK_A] int candidate counts
constexpr int CAND_OFF   = 2 * NBLK_A;           // [NBLK_A*64*2] float2 {ss, idx}
constexpr int PREACT_OFF = CAND_OFF + NBLK_A * 128;  // [5*HDIM]

__device__ __forceinline__ float wave_sum(float v) {
    #pragma unroll
    for (int off = 32; off; off >>= 1) v += __shfl_xor(v, off);
    return v;
}
__device__ __forceinline__ float wave_min(float v) {
    #pragma unroll
    for (int off = 32; off; off >>= 1) v = fminf(v, __shfl_xor(v, off));
    return v;
}
__device__ __forceinline__ float d2sum(float4 a, float4 c) {
    float d, s;
    d = a.x - c.x; s  = d * d;
    d = a.y - c.y; s += d * d;
    d = a.z - c.z; s += d * d;
    d = a.w - c.w; s += d * d;
    return s;
}

// ================= kernel A: preact + balanced sims sweep + candidates =======
__global__ __launch_bounds__(256)
void kA(const float* __restrict__ state, const float* __restrict__ pa,
        const float* __restrict__ pr, const float* __restrict__ ts,
        const float* __restrict__ cue, const float* __restrict__ K,
        const float* __restrict__ Wx, const float* __restrict__ Wh,
        const float* __restrict__ b, const float* __restrict__ h0,
        float* __restrict__ ws) {
    const int lane = threadIdx.x & 63;
    const int wib  = threadIdx.x >> 6;
    const int blk  = blockIdx.x;
    const int gw   = blk * 4 + wib;

    // ---- preact rows (first 2560 waves = blocks 0..639) ----
    if (gw < 5 * HDIM) {
        const int row = gw;
        float x0 = state[lane];
        float x1 = 0.f;
        if      (lane < 4)  x1 = pa[lane];
        else if (lane == 4) x1 = pr[0];
        else if (lane == 5) x1 = ts[0];

        const float4* h04 = (const float4*)h0;
        const float4  hA = h04[lane], hB = h04[64 + lane];
        const float4* wh4 = (const float4*)(Wh + (size_t)row * HDIM);
        const float4 a0 = wh4[lane], a1 = wh4[64 + lane];
        float acc = a0.x*hA.x + a0.y*hA.y + a0.z*hA.z + a0.w*hA.w
                  + a1.x*hB.x + a1.y*hB.y + a1.z*hB.z + a1.w*hB.w;
        const float* wxr = Wx + (size_t)row * 70;
        acc += wxr[lane] * x0;
        if (lane < 6) acc += wxr[64 + lane] * x1;
        acc = wave_sum(acc);
        if (lane == 0) ws[PREACT_OFF + row] = acc + b[row];
    }

    // ---- balanced contiguous row range for this block ----
    int bs, be;
    if (blk < SPLIT_BLKS) {
        bs = (int)(((long long)blk       * SPLIT_ROWS) / SPLIT_BLKS);
        be = (int)(((long long)(blk + 1) * SPLIT_ROWS) / SPLIT_BLKS);
    } else {
        const int rb = blk - SPLIT_BLKS;
        bs = SPLIT_ROWS + (int)(((long long)rb       * (NROWS - SPLIT_ROWS)) / (NBLK_A - SPLIT_BLKS));
        be = SPLIT_ROWS + (int)(((long long)(rb + 1) * (NROWS - SPLIT_ROWS)) / (NBLK_A - SPLIT_BLKS));
    }
    const int rows = be - bs;                    // 45..51 (< 64)

    __shared__ float ssbuf[64];
    __shared__ float swmin[4];

    // ---- per-wave contiguous sub-range, 4-row groups + tail ----
    const int wstart = bs + (rows * wib) / 4;
    const int wend   = bs + (rows * (wib + 1)) / 4;

    const float4* c4 = (const float4*)cue;
    const float4 cA = c4[lane], cB = c4[64 + lane];
    float wmin = INFINITY;

    int r = wstart;
    for (; r + 4 <= wend; r += 4) {
        const float* p = K + (size_t)r * HDIM;
        const float4* p0 = (const float4*)(p);
        const float4* p1 = (const float4*)(p + HDIM);
        const float4* p2 = (const float4*)(p + 2 * HDIM);
        const float4* p3 = (const float4*)(p + 3 * HDIM);
        const float4 a0 = p0[lane], b0 = p0[64 + lane];
        const float4 a1 = p1[lane], b1 = p1[64 + lane];
        const float4 a2 = p2[lane], b2 = p2[64 + lane];
        const float4 a3 = p3[lane], b3 = p3[64 + lane];
        float s0 = d2sum(a0, cA) + d2sum(b0, cB);
        float s1 = d2sum(a1, cA) + d2sum(b1, cB);
        float s2 = d2sum(a2, cA) + d2sum(b2, cB);
        float s3 = d2sum(a3, cA) + d2sum(b3, cB);
        #pragma unroll
        for (int off = 32; off; off >>= 1) {     // 4 independent chains, ILP
            s0 += __shfl_xor(s0, off);
            s1 += __shfl_xor(s1, off);
            s2 += __shfl_xor(s2, off);
            s3 += __shfl_xor(s3, off);
        }
        if (lane == 0) {
            ssbuf[r - bs + 0] = s0;
            ssbuf[r - bs + 1] = s1;
            ssbuf[r - bs + 2] = s2;
            ssbuf[r - bs + 3] = s3;
        }
        wmin = fminf(fminf(wmin, s0), fminf(fminf(s1, s2), s3));
    }
    for (; r < wend; ++r) {                      // 0..3 tail rows
        const float4* p0 = (const float4*)(K + (size_t)r * HDIM);
        const float4 a0 = p0[lane], b0 = p0[64 + lane];
        float s0 = wave_sum(d2sum(a0, cA) + d2sum(b0, cB));
        if (lane == 0) ssbuf[r - bs] = s0;
        wmin = fminf(wmin, s0);
    }

    if (lane == 0) swmin[wib] = wmin;
    __syncthreads();
    const float bminv = fminf(fminf(swmin[0], swmin[1]),
                              fminf(swmin[2], swmin[3]));
    if (threadIdx.x == 0) ws[BMIN_OFF + blk] = bminv;

    // ---- deterministic ballot-compact candidates (wave 0 only) ----
    if (wib == 0) {
        const int t = lane;
        const bool ok = (t < rows) && (ssbuf[t] <= bminv + 30.0f);
        const unsigned long long mask = __ballot(ok);
        if (lane == 0) ((int*)ws)[CNT_OFF + blk] = (int)__popcll(mask);
        if (ok) {
            const int pos = (int)__popcll(mask & ((1ull << t) - 1ull));
            float2* cand = (float2*)(ws + CAND_OFF);
            cand[(blk << 6) + pos] = make_float2(ssbuf[t], __int_as_float(bs + t));
        }
    }
}

// ====== kernel B (single block): min-reduce + survivor gather + cell + heads =
__global__ __launch_bounds__(256)
void kB(const float* __restrict__ V, const float* __restrict__ c0,
        const float* __restrict__ aw, const float* __restrict__ ab,
        const float* __restrict__ cw, const float* __restrict__ cb,
        float* __restrict__ ws, float* __restrict__ out) {
    const int t    = threadIdx.x;   // 256 threads
    const int lane = t & 63;
    const int wib  = t >> 6;

    __shared__ float sred[4];
    __shared__ int   sc[256];
    __shared__ float surv_s[K_CAP];
    __shared__ int   surv_n[K_CAP];
    __shared__ float sden;
    __shared__ float hl[HDIM];
    __shared__ float logits[4];

    // ---- 1) global min of ||K-cue||^2 ----
    float mn = INFINITY;
    #pragma unroll
    for (int j = 0; j < NBLK_A / 256; j++)
        mn = fminf(mn, ws[BMIN_OFF + j * 256 + t]);
    mn = wave_min(mn);
    if (lane == 0) sred[wib] = mn;
    __syncthreads();
    const float smin = fminf(fminf(sred[0], sred[1]), fminf(sred[2], sred[3]));
    const float thr  = smin + 30.0f;

    // ---- 2) survivor scan over candidate lists (two-pass, deterministic) ----
    const int*    cnt  = (const int*)ws + CNT_OFF;
    const float2* cand = (const float2*)(ws + CAND_OFF);

    int mycnt = 0;
    #pragma unroll
    for (int j = 0; j < NBLK_A / 256; j++) {
        const int bidx = t + j * 256;
        const int c = cnt[bidx];
        for (int e = 0; e < c; e++)
            if (cand[(bidx << 6) + e].x <= thr) mycnt++;
    }
    sc[t] = mycnt;
    __syncthreads();
    for (int d = 1; d < 256; d <<= 1) {          // inclusive Hillis-Steele
        int v = (t >= d) ? sc[t - d] : 0;
        __syncthreads();
        sc[t] += v;
        __syncthreads();
    }
    const int total = sc[255];
    int off = sc[t] - mycnt;
    #pragma unroll
    for (int j = 0; j < NBLK_A / 256; j++) {     // pass 2: identical order
        const int bidx = t + j * 256;
        const int c = cnt[bidx];
        for (int e = 0; e < c; e++) {
            const float2 ce = cand[(bidx << 6) + e];
            if (ce.x <= thr) {
                if (off < K_CAP) {
                    surv_s[off] = ce.x;
                    surv_n[off] = __float_as_int(ce.y);
                }
                off++;
            }
        }
    }
    __syncthreads();
    const int tot = (total < K_CAP) ? total : K_CAP;

    // ---- 3) weights + denominator (serial, deterministic order) ----
    if (t == 0) {
        float den = 0.f;
        for (int i = 0; i < tot; i++) {
            const float e = expf(smin - surv_s[i]);  // = exp(sim - smax)
            surv_s[i] = e;
            den += e;
        }
        sden = den;
    }
    __syncthreads();
    const float inv_den = 1.f / sden;

    // ---- 4) m_t = sum_i w_i * V[n_i] / den  (t owns dims t, t+256) ----
    float m0 = 0.f, m1 = 0.f;
    for (int i = 0; i < tot; i++) {
        const float w = surv_s[i];
        const size_t base = (size_t)surv_n[i] * HDIM;
        m0 += w * V[base + t];
        m1 += w * V[base + 256 + t];
    }
    m0 *= inv_den; m1 *= inv_den;

    // ---- 5) LSTM cell + heads ----
    #pragma unroll
    for (int half = 0; half < 2; half++) {
        const int tt = t + half * 256;
        const float mm = half ? m1 : m0;
        const float pf = ws[PREACT_OFF + tt];
        const float pi = ws[PREACT_OFF + HDIM + tt];
        const float po = ws[PREACT_OFF + 2*HDIM + tt];
        const float prg= ws[PREACT_OFF + 3*HDIM + tt];
        const float pc = ws[PREACT_OFF + 4*HDIM + tt];
        const float f_t = 1.f / (1.f + expf(-pf));
        const float i_t = 1.f / (1.f + expf(-pi));
        const float o_t = 1.f / (1.f + expf(-po));
        const float r_t = 1.f / (1.f + expf(-prg));
        const float chat = tanhf(pc);
        const float ct = f_t * c0[tt] + i_t * chat + r_t * mm;
        const float ht = o_t * tanhf(ct);
        out[517 + tt] = ct;
        out[5 + tt]   = ht;
        hl[tt] = ht;
    }
    __syncthreads();

    if (wib < 4) {       // actor logits, one wave per row
        float acc = 0.f;
        #pragma unroll
        for (int j = 0; j < HDIM; j += 64)
            acc += aw[wib * HDIM + j + lane] * hl[j + lane];
        acc = wave_sum(acc);
        if (lane == 0) logits[wib] = acc + ab[wib];
    }
    if (wib == 0) {      // critic
        float acc = 0.f;
        #pragma unroll
        for (int j = 0; j < HDIM; j += 64)
            acc += cw[j + lane] * hl[j + lane];
        acc = wave_sum(acc);
        if (lane == 0) out[4] = acc + cb[0];
    }
    __syncthreads();

    if (t == 0) {
        const float mx = fmaxf(fmaxf(logits[0], logits[1]),
                               fmaxf(logits[2], logits[3]));
        const float e0 = expf(logits[0] - mx), e1 = expf(logits[1] - mx);
        const float e2 = expf(logits[2] - mx), e3 = expf(logits[3] - mx);
        const float inv = 1.f / (e0 + e1 + e2 + e3);
        out[0] = e0 * inv; out[1] = e1 * inv;
        out[2] = e2 * inv; out[3] = e3 * inv;
    }
}

extern "C" void kernel_launch(void* const* d_in, const int* in_sizes, int n_in,
                              void* d_out, int out_size, void* d_ws, size_t ws_size,
                              hipStream_t stream) {
    const float* state  = (const float*)d_in[0];
    const float* pa     = (const float*)d_in[1];
    const float* pr     = (const float*)d_in[2];
    const float* ts     = (const float*)d_in[3];
    const float* cue    = (const float*)d_in[4];
    const float* keys   = (const float*)d_in[5];
    const float* vals   = (const float*)d_in[6];
    const float* Wx     = (const float*)d_in[7];
    const float* Wh     = (const float*)d_in[8];
    const float* b      = (const float*)d_in[9];
    const float* aw     = (const float*)d_in[10];
    const float* ab     = (const float*)d_in[11];
    const float* cw     = (const float*)d_in[12];
    const float* cb     = (const float*)d_in[13];
    const float* h0     = (const float*)d_in[14];
    const float* c0     = (const float*)d_in[15];
    float* ws  = (float*)d_ws;
    float* out = (float*)d_out;

    kA<<<NBLK_A, 256, 0, stream>>>(state, pa, pr, ts, cue, keys, Wx, Wh, b, h0, ws);
    kB<<<1, 256, 0, stream>>>(vals, c0, aw, ab, cw, cb, ws, out);
}